// Round 3
// baseline (15658.649 us; speedup 1.0000x reference)
//
#include <hip/hip_runtime.h>
#include <hip/hip_bf16.h>
#include <hip/hip_cooperative_groups.h>

namespace cg = cooperative_groups;

typedef __attribute__((ext_vector_type(8))) short short8;
typedef __attribute__((ext_vector_type(4))) float floatx4;
typedef __hip_bfloat16 bf16;

#define MFMA16(a,b,c) __builtin_amdgcn_mfma_f32_16x16x32_bf16((a),(b),(c),0,0,0)

__device__ __forceinline__ short8 ldf(const bf16* p){ return *(const short8*)p; }
__device__ __forceinline__ float fsig(float x){ return 1.f/(1.f+__expf(-x)); }
__device__ __forceinline__ float ftanh(float x){
  float c = fminf(fmaxf(x,-15.f),15.f);
  float e = __expf(2.f*c);
  return (e-1.f)/(e+1.f);
}

// ---------------- weight prep: fp32 [R][C] -> bf16 [C][R] ----------------
__global__ __launch_bounds__(256) void k_transpose(const float* __restrict__ in,
                                                   bf16* __restrict__ out, int R, int C){
  __shared__ float t[32][33];
  int bc = blockIdx.x*32, br = blockIdx.y*32;
  int tx = threadIdx.x & 31, ty = threadIdx.x >> 5; // 32 x 8
  #pragma unroll
  for (int i=0;i<32;i+=8) t[ty+i][tx] = in[(size_t)(br+ty+i)*C + bc+tx];
  __syncthreads();
  #pragma unroll
  for (int i=0;i<32;i+=8) out[(size_t)(bc+ty+i)*R + br+tx] = __float2bfloat16(t[tx][ty+i]);
}

__global__ __launch_bounds__(256) void k_cast(const float* __restrict__ in, bf16* __restrict__ out, int n){
  int i = blockIdx.x*256+threadIdx.x;
  if (i<n) out[i] = __float2bfloat16(in[i]);
}

// state [256,64] -> PIN cols 0:64 (PIN row stride 192)
__global__ __launch_bounds__(256) void k_cast_state(const float* __restrict__ st, bf16* __restrict__ pin){
  int i = blockIdx.x*256+threadIdx.x; // 16384
  int r = i >> 6, c = i & 63;
  pin[r*192 + c] = __float2bfloat16(st[i]);
}

// act MLP hidden: H1[(t*256+b)][c] = tanh(sum_i act[b][t][i]*w1[i][c] + b1[c])
__global__ __launch_bounds__(256) void k_acth1(const float* __restrict__ act,
                                               const float* __restrict__ w1,
                                               const float* __restrict__ b1,
                                               bf16* __restrict__ H1){
  int idx = blockIdx.x*256 + threadIdx.x;          // 16384*512
  int c = idx & 511; int r = idx >> 9;             // r = t*256+b
  int t = r >> 8, b = r & 255;
  const float* a = act + (b*64 + t)*6;
  float s = b1[c];
  #pragma unroll
  for (int i=0;i<6;i++) s += a[i]*w1[i*512+c];
  H1[r*512+c] = __float2bfloat16(ftanh(s));
}

// ---------------- generic GEMM: out[m][j] = act(A[m,:K] . Bt[j,:K] + bias[j]) ----------------
__global__ __launch_bounds__(256) void k_gemm16(
  const bf16* __restrict__ A, int sA,
  const bf16* __restrict__ Bt,
  const float* __restrict__ bias,
  bf16* __restrict__ out, int sO, int oO,
  int K, int mode)
{
  int lane = threadIdx.x & 63, wave = threadIdx.x >> 6;
  int lr = lane & 15, lq = lane >> 4;
  int j0 = blockIdx.x*64 + wave*16;
  int m0 = blockIdx.y*16;
  const bf16* Ap = A + (m0+lr)*sA + lq*8;
  const bf16* Bp = Bt + (j0+lr)*K + lq*8;
  floatx4 acc = {0.f,0.f,0.f,0.f};
  #pragma unroll 4
  for (int kb=0; kb<K; kb+=32){
    short8 a = ldf(Ap+kb);
    short8 b = ldf(Bp+kb);
    acc = MFMA16(a, b, acc);
  }
  #pragma unroll
  for (int i=0;i<4;i++){
    int m = m0 + lq*4 + i, j = j0 + lr;
    float v = acc[i] + bias[j];
    if (mode) v = ftanh(v);
    out[m*sO + oO + j] = __float2bfloat16(v);
  }
}

// ---------------- gaussian head: z = mu + exp(ls)*eps ----------------
__global__ __launch_bounds__(256) void k_gauss(
  const bf16* __restrict__ A, const bf16* __restrict__ Bt,
  const float* __restrict__ bias, const float* __restrict__ eps,
  bf16* __restrict__ out, int K)
{
  int lane = threadIdx.x & 63, wave = threadIdx.x >> 6;
  int lr = lane & 15, lq = lane >> 4;
  int j0 = blockIdx.x*64 + wave*16;
  int m0 = blockIdx.y*16;
  const bf16* Ap = A + (m0+lr)*K + lq*8;
  const bf16* Bm = Bt + (j0+lr)*K + lq*8;
  const bf16* Bl = Bt + (j0+1024+lr)*K + lq*8;
  floatx4 aM = {0.f,0.f,0.f,0.f}, aL = {0.f,0.f,0.f,0.f};
  #pragma unroll 4
  for (int kb=0;kb<K;kb+=32){
    short8 a = ldf(Ap+kb);
    aM = MFMA16(a, ldf(Bm+kb), aM);
    aL = MFMA16(a, ldf(Bl+kb), aL);
  }
  #pragma unroll
  for (int i=0;i<4;i++){
    int m = m0+lq*4+i, j = j0+lr;
    float z = aM[i] + bias[j] + __expf(aL[i] + bias[1024+j]) * eps[m*1024 + j];
    out[m*1024+j] = __float2bfloat16(z);
  }
}

// ---------------- fused GRU step (fallback path, round-1 proven) ----------------
__global__ __launch_bounds__(256) void k_gru(
  const bf16* __restrict__ Z, const bf16* __restrict__ H, const bf16* __restrict__ AEt,
  const bf16* __restrict__ WzT, const bf16* __restrict__ WhT, const bf16* __restrict__ WaT,
  const float* __restrict__ bih, const float* __restrict__ bhh,
  bf16* __restrict__ Hout)
{
  int lane = threadIdx.x & 63, wave = threadIdx.x >> 6;
  int lr = lane & 15, lq = lane >> 4;
  int wg = blockIdx.x;
  int m0 = (wg >> 4) * 16;
  int j0 = ((wg & 15)*4 + wave) * 16;

  floatx4 aR = {0.f,0.f,0.f,0.f}, aU = aR, aN = aR, aHN = aR;
  {
    const bf16* Ap = Z + (m0+lr)*1024 + lq*8;
    const bf16* Br = WzT + (j0+lr)*1024 + lq*8;
    const bf16* Bu = WzT + (j0+1024+lr)*1024 + lq*8;
    const bf16* Bn = WzT + (j0+2048+lr)*1024 + lq*8;
    #pragma unroll 4
    for (int kb=0; kb<1024; kb+=32){
      short8 a = ldf(Ap+kb);
      aR = MFMA16(a, ldf(Br+kb), aR);
      aU = MFMA16(a, ldf(Bu+kb), aU);
      aN = MFMA16(a, ldf(Bn+kb), aN);
    }
  }
  {
    const bf16* Ap = H + (m0+lr)*1024 + lq*8;
    const bf16* Br = WhT + (j0+lr)*1024 + lq*8;
    const bf16* Bu = WhT + (j0+1024+lr)*1024 + lq*8;
    const bf16* Bn = WhT + (j0+2048+lr)*1024 + lq*8;
    #pragma unroll 4
    for (int kb=0; kb<1024; kb+=32){
      short8 a = ldf(Ap+kb);
      aR = MFMA16(a, ldf(Br+kb), aR);
      aU = MFMA16(a, ldf(Bu+kb), aU);
      aHN = MFMA16(a, ldf(Bn+kb), aHN);
    }
  }
  {
    const bf16* Ap = AEt + (m0+lr)*512 + lq*8;
    const bf16* Br = WaT + (j0+lr)*512 + lq*8;
    const bf16* Bu = WaT + (j0+1024+lr)*512 + lq*8;
    const bf16* Bn = WaT + (j0+2048+lr)*512 + lq*8;
    #pragma unroll 4
    for (int kb=0; kb<512; kb+=32){
      short8 a = ldf(Ap+kb);
      aR = MFMA16(a, ldf(Br+kb), aR);
      aU = MFMA16(a, ldf(Bu+kb), aU);
      aN = MFMA16(a, ldf(Bn+kb), aN);
    }
  }
  #pragma unroll
  for (int i=0;i<4;i++){
    int m = m0 + lq*4 + i, j = j0 + lr;
    float r = fsig(aR[i] + bih[j] + bhh[j]);
    float u = fsig(aU[i] + bih[1024+j] + bhh[1024+j]);
    float n = ftanh(aN[i] + bih[2048+j] + r*(aHN[i] + bhh[2048+j]));
    float h = __bfloat162float(H[m*1024+j]);
    Hout[m*1024+j] = __float2bfloat16((1.f-u)*n + u*h);
  }
}

// ---------------- persistent cooperative scan kernel ----------------
__global__ __launch_bounds__(256,1) void k_scan(
  const bf16* __restrict__ AEb,
  const bf16* __restrict__ WzT, const bf16* __restrict__ WhT, const bf16* __restrict__ WaT,
  const float* __restrict__ bih, const float* __restrict__ bhh,
  const bf16* __restrict__ Lw1, const float* __restrict__ Lb1,
  const bf16* __restrict__ Lw2, const float* __restrict__ Lb2,
  const float* __restrict__ epss,
  bf16* __restrict__ Zbuf, bf16* __restrict__ Hbuf, bf16* __restrict__ Xs)
{
  cg::grid_group grid = cg::this_grid();
  __shared__ float lds[4][16][64][4];
  const int tid = threadIdx.x;
  const int lane = tid & 63, w = tid >> 6;
  const int lr = lane & 15, lq = lane >> 4;
  const int blk = blockIdx.x;
  const int j0 = (blk & 63) * 16;
  const int m0 = (blk >> 6) * 64;
  const int jl = j0 + lr;

  for (int t = 0; t < 64; t++){
    const bf16* Z  = Zbuf + (size_t)t * 262144;
    const bf16* H  = Hbuf + (size_t)t * 262144;
    bf16* Hn = Hbuf + (size_t)(t+1) * 262144;
    bf16* Zn = Zbuf + (size_t)(t+1) * 262144;
    const bf16* AE = AEb + (size_t)t * 131072;

    // ---------- Phase A: GRU ----------
    floatx4 R[4]={}, U[4]={}, NX[4]={}, NH[4]={};
    const int c0 = w * 640, c1 = c0 + 640;

#define SEG(Abase, sA, Wt, Kw, gb, glen, NACC) { \
    int lo = c0 > (gb) ? c0 : (gb); \
    int hi = c1 < (gb)+(glen) ? c1 : (gb)+(glen); \
    for (int k = lo; k < hi; k += 32){ \
      int kk = k - (gb); \
      const bf16* ap = (Abase) + kk + lq*8; \
      short8 a0 = ldf(ap + (m0      + lr)*(sA)); \
      short8 a1 = ldf(ap + (m0 + 16 + lr)*(sA)); \
      short8 a2 = ldf(ap + (m0 + 32 + lr)*(sA)); \
      short8 a3 = ldf(ap + (m0 + 48 + lr)*(sA)); \
      const bf16* bp = (Wt) + kk + lq*8; \
      short8 br = ldf(bp + (size_t)(jl       )*(Kw)); \
      short8 bu = ldf(bp + (size_t)(jl + 1024)*(Kw)); \
      short8 bn = ldf(bp + (size_t)(jl + 2048)*(Kw)); \
      R[0]=MFMA16(a0,br,R[0]); U[0]=MFMA16(a0,bu,U[0]); NACC[0]=MFMA16(a0,bn,NACC[0]); \
      R[1]=MFMA16(a1,br,R[1]); U[1]=MFMA16(a1,bu,U[1]); NACC[1]=MFMA16(a1,bn,NACC[1]); \
      R[2]=MFMA16(a2,br,R[2]); U[2]=MFMA16(a2,bu,U[2]); NACC[2]=MFMA16(a2,bn,NACC[2]); \
      R[3]=MFMA16(a3,br,R[3]); U[3]=MFMA16(a3,bu,U[3]); NACC[3]=MFMA16(a3,bn,NACC[3]); \
    } }

    SEG(Z, 1024, WzT, 1024, 0,    1024, NX)
    SEG(AE, 512, WaT, 512,  1024, 512,  NX)
    SEG(H, 1024, WhT, 1024, 1536, 1024, NH)
#undef SEG

    #pragma unroll
    for (int mf=0; mf<4; mf++){
      *(floatx4*)&lds[w][mf    ][lane][0] = R[mf];
      *(floatx4*)&lds[w][4 +mf ][lane][0] = U[mf];
      *(floatx4*)&lds[w][8 +mf ][lane][0] = NX[mf];
      *(floatx4*)&lds[w][12+mf ][lane][0] = NH[mf];
    }
    __syncthreads();
    {
      const int mf = w;
      floatx4 sR={}, sU={}, sNX={}, sNH={};
      #pragma unroll
      for (int ww=0; ww<4; ww++){
        sR += *(const floatx4*)&lds[ww][mf    ][lane][0];
        sU += *(const floatx4*)&lds[ww][4 +mf ][lane][0];
        sNX+= *(const floatx4*)&lds[ww][8 +mf ][lane][0];
        sNH+= *(const floatx4*)&lds[ww][12+mf ][lane][0];
      }
      float bR  = bih[jl] + bhh[jl];
      float bU  = bih[1024+jl] + bhh[1024+jl];
      float bNX = bih[2048+jl];
      float bNH = bhh[2048+jl];
      #pragma unroll
      for (int i=0;i<4;i++){
        int m = m0 + mf*16 + lq*4 + i;
        float r = fsig(sR[i]+bR);
        float u = fsig(sU[i]+bU);
        float n = ftanh(sNX[i]+bNX + r*(sNH[i]+bNH));
        float h = __bfloat162float(H[m*1024 + jl]);
        Hn[m*1024 + jl] = __float2bfloat16((1.f-u)*n + u*h);
      }
    }
    __threadfence();
    grid.sync();
    __threadfence();   // acquire: invalidate stale cache lines before cross-block reads

    // ---------- Phase B: X = tanh(Hn @ lsd_w1 + b1) ----------
    {
      floatx4 C[4]={};
      int kb0 = w*256;
      for (int k=kb0; k<kb0+256; k+=32){
        const bf16* ap = Hn + k + lq*8;
        short8 a0 = ldf(ap + (m0      + lr)*1024);
        short8 a1 = ldf(ap + (m0 + 16 + lr)*1024);
        short8 a2 = ldf(ap + (m0 + 32 + lr)*1024);
        short8 a3 = ldf(ap + (m0 + 48 + lr)*1024);
        short8 bb = ldf(Lw1 + (size_t)jl*1024 + k + lq*8);
        C[0]=MFMA16(a0,bb,C[0]); C[1]=MFMA16(a1,bb,C[1]);
        C[2]=MFMA16(a2,bb,C[2]); C[3]=MFMA16(a3,bb,C[3]);
      }
      #pragma unroll
      for (int mf=0; mf<4; mf++) *(floatx4*)&lds[w][mf][lane][0] = C[mf];
      __syncthreads();
      const int mf = w;
      floatx4 s={};
      #pragma unroll
      for (int ww=0; ww<4; ww++) s += *(const floatx4*)&lds[ww][mf][lane][0];
      float bb = Lb1[jl];
      #pragma unroll
      for (int i=0;i<4;i++){
        int m = m0 + mf*16 + lq*4 + i;
        Xs[m*1024 + jl] = __float2bfloat16(ftanh(s[i]+bb));
      }
    }
    __threadfence();
    grid.sync();
    __threadfence();

    // ---------- Phase C: Zn = mu + exp(ls)*eps ----------
    {
      floatx4 MU[4]={}, LSa[4]={};
      int kb0 = w*256;
      for (int k=kb0; k<kb0+256; k+=32){
        const bf16* ap = Xs + k + lq*8;
        short8 a0 = ldf(ap + (m0      + lr)*1024);
        short8 a1 = ldf(ap + (m0 + 16 + lr)*1024);
        short8 a2 = ldf(ap + (m0 + 32 + lr)*1024);
        short8 a3 = ldf(ap + (m0 + 48 + lr)*1024);
        short8 bm = ldf(Lw2 + (size_t)jl*1024 + k + lq*8);
        short8 bl = ldf(Lw2 + (size_t)(1024+jl)*1024 + k + lq*8);
        MU[0]=MFMA16(a0,bm,MU[0]); LSa[0]=MFMA16(a0,bl,LSa[0]);
        MU[1]=MFMA16(a1,bm,MU[1]); LSa[1]=MFMA16(a1,bl,LSa[1]);
        MU[2]=MFMA16(a2,bm,MU[2]); LSa[2]=MFMA16(a2,bl,LSa[2]);
        MU[3]=MFMA16(a3,bm,MU[3]); LSa[3]=MFMA16(a3,bl,LSa[3]);
      }
      #pragma unroll
      for (int mf=0; mf<4; mf++){
        *(floatx4*)&lds[w][mf   ][lane][0] = MU[mf];
        *(floatx4*)&lds[w][4+mf ][lane][0] = LSa[mf];
      }
      __syncthreads();
      const int mf = w;
      floatx4 sM={}, sL={};
      #pragma unroll
      for (int ww=0; ww<4; ww++){
        sM += *(const floatx4*)&lds[ww][mf  ][lane][0];
        sL += *(const floatx4*)&lds[ww][4+mf][lane][0];
      }
      float bmu = Lb2[jl], bls = Lb2[1024+jl];
      #pragma unroll
      for (int i=0;i<4;i++){
        int m = m0 + mf*16 + lq*4 + i;
        float z = sM[i]+bmu + __expf(sL[i]+bls) * epss[(size_t)t*262144 + m*1024 + jl];
        Zn[m*1024 + jl] = __float2bfloat16(z);
      }
    }
    __threadfence();
    grid.sync();
    __threadfence();
  }
}

// ---------------- decode: Y1 = tanh(din @ dec_w1 + b) ----------------
__global__ __launch_bounds__(256) void k_dec1(
  const bf16* __restrict__ Zb, const bf16* __restrict__ Hb,
  const bf16* __restrict__ W, const float* __restrict__ bias,
  bf16* __restrict__ Y)
{
  int lane = threadIdx.x & 63, wave = threadIdx.x >> 6;
  int lr = lane & 15, lq = lane >> 4;
  int m0 = blockIdx.y * 32;
  int j0 = blockIdx.x * 256 + wave * 64;
  floatx4 acc[2][4] = {};
  const bf16* Az = Zb + 256*1024;
  const bf16* Ah = Hb + 256*1024;
  #pragma unroll 2
  for (int kb=0; kb<1024; kb+=32){
    short8 a0 = ldf(Az + (m0+lr)*1024 + kb + lq*8);
    short8 a1 = ldf(Az + (m0+16+lr)*1024 + kb + lq*8);
    #pragma unroll
    for (int c=0;c<4;c++){
      short8 b = ldf(W + (size_t)(j0+c*16+lr)*2048 + kb + lq*8);
      acc[0][c] = MFMA16(a0,b,acc[0][c]);
      acc[1][c] = MFMA16(a1,b,acc[1][c]);
    }
  }
  #pragma unroll 2
  for (int kb=0; kb<1024; kb+=32){
    short8 a0 = ldf(Ah + (m0+lr)*1024 + kb + lq*8);
    short8 a1 = ldf(Ah + (m0+16+lr)*1024 + kb + lq*8);
    #pragma unroll
    for (int c=0;c<4;c++){
      short8 b = ldf(W + (size_t)(j0+c*16+lr)*2048 + 1024 + kb + lq*8);
      acc[0][c] = MFMA16(a0,b,acc[0][c]);
      acc[1][c] = MFMA16(a1,b,acc[1][c]);
    }
  }
  #pragma unroll
  for (int rf=0;rf<2;rf++)
    #pragma unroll
    for (int c=0;c<4;c++)
      #pragma unroll
      for (int i=0;i<4;i++){
        int m = m0 + rf*16 + lq*4 + i;
        int j = j0 + c*16 + lr;
        Y[m*1024 + j] = __float2bfloat16(ftanh(acc[rf][c][i] + bias[j]));
      }
}

// obs_pred = Y1 @ dec_w2 + b -> out[b][t][0:512]
__global__ __launch_bounds__(256) void k_out1(
  const bf16* __restrict__ Y, const bf16* __restrict__ W, const float* __restrict__ bias,
  float* __restrict__ out)
{
  int lane = threadIdx.x & 63, wave = threadIdx.x >> 6;
  int lr = lane & 15, lq = lane >> 4;
  int m0 = blockIdx.y * 32;
  int j0 = blockIdx.x * 256 + wave * 64;
  floatx4 acc[2][4] = {};
  #pragma unroll 2
  for (int kb=0; kb<1024; kb+=32){
    short8 a0 = ldf(Y + (m0+lr)*1024 + kb + lq*8);
    short8 a1 = ldf(Y + (m0+16+lr)*1024 + kb + lq*8);
    #pragma unroll
    for (int c=0;c<4;c++){
      short8 b = ldf(W + (size_t)(j0+c*16+lr)*1024 + kb + lq*8);
      acc[0][c] = MFMA16(a0,b,acc[0][c]);
      acc[1][c] = MFMA16(a1,b,acc[1][c]);
    }
  }
  #pragma unroll
  for (int rf=0;rf<2;rf++)
    #pragma unroll
    for (int c=0;c<4;c++)
      #pragma unroll
      for (int i=0;i<4;i++){
        int m = m0 + rf*16 + lq*4 + i;
        int j = j0 + c*16 + lr;
        int b = m & 255, t = m >> 8;
        out[b*40960 + t*640 + j] = acc[rf][c][i] + bias[j];
      }
}

// state decoder
__global__ __launch_bounds__(256) void k_sd(
  const bf16* __restrict__ Zb, const bf16* __restrict__ Hb,
  const bf16* __restrict__ W, const float* __restrict__ bias,
  float* __restrict__ out)
{
  int lane = threadIdx.x & 63, wave = threadIdx.x >> 6;
  int lr = lane & 15, lq = lane >> 4;
  int m0 = blockIdx.x * 32;
  int j0 = wave * 16;
  floatx4 aM[2] = {}, aL[2] = {};
  const bf16* Az = Zb + 256*1024;
  const bf16* Ah = Hb + 256*1024;
  #pragma unroll 2
  for (int kb=0; kb<1024; kb+=32){
    short8 a0 = ldf(Az + (m0+lr)*1024 + kb + lq*8);
    short8 a1 = ldf(Az + (m0+16+lr)*1024 + kb + lq*8);
    short8 bm = ldf(W + (size_t)(j0+lr)*2048 + kb + lq*8);
    short8 bl = ldf(W + (size_t)(j0+64+lr)*2048 + kb + lq*8);
    aM[0] = MFMA16(a0,bm,aM[0]); aM[1] = MFMA16(a1,bm,aM[1]);
    aL[0] = MFMA16(a0,bl,aL[0]); aL[1] = MFMA16(a1,bl,aL[1]);
  }
  #pragma unroll 2
  for (int kb=0; kb<1024; kb+=32){
    short8 a0 = ldf(Ah + (m0+lr)*1024 + kb + lq*8);
    short8 a1 = ldf(Ah + (m0+16+lr)*1024 + kb + lq*8);
    short8 bm = ldf(W + (size_t)(j0+lr)*2048 + 1024 + kb + lq*8);
    short8 bl = ldf(W + (size_t)(j0+64+lr)*2048 + 1024 + kb + lq*8);
    aM[0] = MFMA16(a0,bm,aM[0]); aM[1] = MFMA16(a1,bm,aM[1]);
    aL[0] = MFMA16(a0,bl,aL[0]); aL[1] = MFMA16(a1,bl,aL[1]);
  }
  #pragma unroll
  for (int rf=0;rf<2;rf++)
    #pragma unroll
    for (int i=0;i<4;i++){
      int m = m0 + rf*16 + lq*4 + i;
      int j = j0 + lr;
      int b = m & 255, t = m >> 8;
      out[b*40960 + t*640 + 512 + j] = aM[rf][i] + bias[j];
      out[b*40960 + t*640 + 576 + j] = __expf(aL[rf][i] + bias[64+j]);
    }
}

extern "C" void kernel_launch(void* const* d_in, const int* in_sizes, int n_in,
                              void* d_out, int out_size, void* d_ws, size_t ws_size,
                              hipStream_t stream)
{
  const float* obs    = (const float*)d_in[0];
  const float* state  = (const float*)d_in[1];
  const float* act    = (const float*)d_in[2];
  const float* eps0   = (const float*)d_in[3];
  const float* epss   = (const float*)d_in[4];
  const float* enc_w1 = (const float*)d_in[5];  const float* enc_b1 = (const float*)d_in[6];
  const float* enc_w2 = (const float*)d_in[7];  const float* enc_b2 = (const float*)d_in[8];
  const float* post_w1= (const float*)d_in[9];  const float* post_b1= (const float*)d_in[10];
  const float* post_w2= (const float*)d_in[11]; const float* post_b2= (const float*)d_in[12];
  const float* amlp_w1= (const float*)d_in[13]; const float* amlp_b1= (const float*)d_in[14];
  const float* amlp_w2= (const float*)d_in[15]; const float* amlp_b2= (const float*)d_in[16];
  const float* gwih   = (const float*)d_in[17];
  const float* gwhh   = (const float*)d_in[18];
  const float* gbih   = (const float*)d_in[19];
  const float* gbhh   = (const float*)d_in[20];
  const float* lsd_w1 = (const float*)d_in[21]; const float* lsd_b1 = (const float*)d_in[22];
  const float* lsd_w2 = (const float*)d_in[23]; const float* lsd_b2 = (const float*)d_in[24];
  const float* dec_w1 = (const float*)d_in[25]; const float* dec_b1 = (const float*)d_in[26];
  const float* dec_w2 = (const float*)d_in[27]; const float* dec_b2 = (const float*)d_in[28];
  const float* sd_w   = (const float*)d_in[29]; const float* sd_b   = (const float*)d_in[30];
  float* out = (float*)d_out;

  char* w = (char*)d_ws;
  size_t off = 0;
  auto alloc = [&](size_t elems)->bf16* {
    bf16* p = (bf16*)(w + off);
    off += ((elems*2 + 255)/256)*256;
    return p;
  };
  bf16* WzT      = alloc((size_t)3072*1024);
  bf16* WhT      = alloc((size_t)3072*1024);
  bf16* WaT      = alloc((size_t)3072*512);
  bf16* lsd_w1T  = alloc((size_t)1024*1024);
  bf16* lsd_w2T  = alloc((size_t)2048*1024);
  bf16* dec_w1T  = alloc((size_t)1024*2048);
  bf16* dec_w2T  = alloc((size_t)512*1024);
  bf16* sd_wT    = alloc((size_t)128*2048);
  bf16* enc_w1T  = alloc((size_t)512*512);
  bf16* enc_w2T  = alloc((size_t)256*512);
  bf16* post_w1sT= alloc((size_t)1024*192);
  bf16* post_w2T = alloc((size_t)2048*1024);
  bf16* amlp_w2T = alloc((size_t)512*512);
  bf16* obsb     = alloc((size_t)256*512);
  bf16* E1       = alloc((size_t)256*512);
  bf16* PIN      = alloc((size_t)256*192);
  bf16* P1       = alloc((size_t)256*1024);
  bf16* X        = alloc((size_t)256*1024);
  bf16* Zbuf     = alloc((size_t)65*256*1024);
  bf16* Hbuf     = alloc((size_t)65*256*1024);
  bf16* AEb      = alloc((size_t)16384*512);
  bf16* Y1       = alloc((size_t)16384*1024);
  bf16* H1       = Y1;   // H1 (16 MiB) dead before Y1 is written

  // --- weight prep ---
  #define TP(src, dst, R, C) k_transpose<<<dim3((C)/32,(R)/32),256,0,stream>>>((src),(dst),(R),(C))
  TP(enc_w1, enc_w1T, 512, 512);
  TP(enc_w2, enc_w2T, 512, 256);
  TP(post_w1 + (size_t)1024*1024, post_w1sT, 192, 1024);
  TP(post_w2, post_w2T, 1024, 2048);
  TP(amlp_w2, amlp_w2T, 512, 512);
  TP(gwih, WzT, 1024, 3072);
  TP(gwih + (size_t)1024*3072, WaT, 512, 3072);
  TP(gwhh, WhT, 1024, 3072);
  TP(lsd_w1, lsd_w1T, 1024, 1024);
  TP(lsd_w2, lsd_w2T, 1024, 2048);
  TP(dec_w1, dec_w1T, 2048, 1024);
  TP(dec_w2, dec_w2T, 1024, 512);
  TP(sd_w, sd_wT, 2048, 128);
  #undef TP

  k_cast<<<512,256,0,stream>>>(obs, obsb, 256*512);
  k_cast_state<<<64,256,0,stream>>>(state, PIN);
  k_acth1<<<32768,256,0,stream>>>(act, amlp_w1, amlp_b1, H1);

  hipMemsetAsync(Hbuf, 0, (size_t)256*1024*2, stream);

  k_gemm16<<<dim3(8,16),256,0,stream>>>(obsb, 512, enc_w1T, enc_b1, E1, 512, 0, 512, 1);
  k_gemm16<<<dim3(2,16),256,0,stream>>>(E1, 512, enc_w2T, enc_b2, PIN, 192, 64, 512, 0);
  k_gemm16<<<dim3(16,16),256,0,stream>>>(PIN, 192, post_w1sT, post_b1, P1, 1024, 0, 192, 1);
  k_gauss<<<dim3(16,16),256,0,stream>>>(P1, post_w2T, post_b2, eps0, Zbuf, 1024);
  k_gemm16<<<dim3(8,1024),256,0,stream>>>(H1, 512, amlp_w2T, amlp_b2, AEb, 512, 0, 512, 0);

  // --- persistent cooperative scan; fall back to per-step loop on launch error ---
  hipError_t cerr;
  {
    void* kArgs[] = {
      (void*)&AEb, (void*)&WzT, (void*)&WhT, (void*)&WaT,
      (void*)&gbih, (void*)&gbhh,
      (void*)&lsd_w1T, (void*)&lsd_b1, (void*)&lsd_w2T, (void*)&lsd_b2,
      (void*)&epss, (void*)&Zbuf, (void*)&Hbuf, (void*)&X
    };
    cerr = hipLaunchCooperativeKernel((const void*)k_scan, dim3(256), dim3(256), kArgs, 0, stream);
  }
  if (cerr != hipSuccess){
    // fallback: round-1 proven 3-kernel-per-step loop
    for (int t=0; t<64; t++){
      const bf16* Zt = Zbuf + (size_t)t*256*1024;
      const bf16* Ht = Hbuf + (size_t)t*256*1024;
      bf16* Htn = Hbuf + (size_t)(t+1)*256*1024;
      bf16* Ztn = Zbuf + (size_t)(t+1)*256*1024;
      k_gru<<<256,256,0,stream>>>(Zt, Ht, AEb + (size_t)t*256*512, WzT, WhT, WaT, gbih, gbhh, Htn);
      k_gemm16<<<dim3(16,16),256,0,stream>>>(Htn, 1024, lsd_w1T, lsd_b1, X, 1024, 0, 1024, 1);
      k_gauss<<<dim3(16,16),256,0,stream>>>(X, lsd_w2T, lsd_b2, epss + (size_t)t*256*1024, Ztn, 1024);
    }
  }

  // --- decode ---
  k_dec1<<<dim3(4,512),256,0,stream>>>(Zbuf, Hbuf, dec_w1T, dec_b1, Y1);
  k_out1<<<dim3(2,512),256,0,stream>>>(Y1, dec_w2T, dec_b2, out);
  k_sd<<<512,256,0,stream>>>(Zbuf, Hbuf, sd_wT, sd_b, out);
}

// Round 4
// 4516.735 us; speedup vs baseline: 3.4668x; 3.4668x over previous
//
#include <hip/hip_runtime.h>
#include <hip/hip_bf16.h>

typedef __attribute__((ext_vector_type(8))) short short8;
typedef __attribute__((ext_vector_type(4))) float floatx4;
typedef __hip_bfloat16 bf16;

#define MFMA16(a,b,c) __builtin_amdgcn_mfma_f32_16x16x32_bf16((a),(b),(c),0,0,0)

__device__ __forceinline__ short8 ldf(const bf16* p){ return *(const short8*)p; }
__device__ __forceinline__ float fsig(float x){ return 1.f/(1.f+__expf(-x)); }
__device__ __forceinline__ float ftanh(float x){
  float c = fminf(fmaxf(x,-15.f),15.f);
  float e = __expf(2.f*c);
  return (e-1.f)/(e+1.f);
}

typedef __attribute__((address_space(1))) void gvoid;
typedef __attribute__((address_space(3))) void lvoid;
// async global->LDS, 16B per lane; LDS dest = uniform base + lane*16
__device__ __forceinline__ void stage16(const bf16* g, bf16* l){
  __builtin_amdgcn_global_load_lds((gvoid*)g, (lvoid*)l, 16, 0, 0);
}

// ---------------- weight prep: fp32 [R][C] -> bf16 [C][R] ----------------
__global__ __launch_bounds__(256) void k_transpose(const float* __restrict__ in,
                                                   bf16* __restrict__ out, int R, int C){
  __shared__ float t[32][33];
  int bc = blockIdx.x*32, br = blockIdx.y*32;
  int tx = threadIdx.x & 31, ty = threadIdx.x >> 5;
  #pragma unroll
  for (int i=0;i<32;i+=8) t[ty+i][tx] = in[(size_t)(br+ty+i)*C + bc+tx];
  __syncthreads();
  #pragma unroll
  for (int i=0;i<32;i+=8) out[(size_t)(bc+ty+i)*R + br+tx] = __float2bfloat16(t[tx][ty+i]);
}

__global__ __launch_bounds__(256) void k_cast(const float* __restrict__ in, bf16* __restrict__ out, int n){
  int i = blockIdx.x*256+threadIdx.x;
  if (i<n) out[i] = __float2bfloat16(in[i]);
}

__global__ __launch_bounds__(256) void k_cast_state(const float* __restrict__ st, bf16* __restrict__ pin){
  int i = blockIdx.x*256+threadIdx.x; // 16384
  int r = i >> 6, c = i & 63;
  pin[r*192 + c] = __float2bfloat16(st[i]);
}

__global__ __launch_bounds__(256) void k_acth1(const float* __restrict__ act,
                                               const float* __restrict__ w1,
                                               const float* __restrict__ b1,
                                               bf16* __restrict__ H1){
  int idx = blockIdx.x*256 + threadIdx.x;
  int c = idx & 511; int r = idx >> 9;
  int t = r >> 8, b = r & 255;
  const float* a = act + (b*64 + t)*6;
  float s = b1[c];
  #pragma unroll
  for (int i=0;i<6;i++) s += a[i]*w1[i*512+c];
  H1[r*512+c] = __float2bfloat16(ftanh(s));
}

// ---------------- generic GEMM (setup path only) ----------------
__global__ __launch_bounds__(256) void k_gemm16(
  const bf16* __restrict__ A, int sA,
  const bf16* __restrict__ Bt,
  const float* __restrict__ bias,
  bf16* __restrict__ out, int sO, int oO,
  int K, int mode)
{
  int lane = threadIdx.x & 63, wave = threadIdx.x >> 6;
  int lr = lane & 15, lq = lane >> 4;
  int j0 = blockIdx.x*64 + wave*16;
  int m0 = blockIdx.y*16;
  const bf16* Ap = A + (m0+lr)*sA + lq*8;
  const bf16* Bp = Bt + (j0+lr)*K + lq*8;
  floatx4 acc = {0.f,0.f,0.f,0.f};
  #pragma unroll 4
  for (int kb=0; kb<K; kb+=32){
    short8 a = ldf(Ap+kb);
    short8 b = ldf(Bp+kb);
    acc = MFMA16(a, b, acc);
  }
  #pragma unroll
  for (int i=0;i<4;i++){
    int m = m0 + lq*4 + i, j = j0 + lr;
    float v = acc[i] + bias[j];
    if (mode) v = ftanh(v);
    out[m*sO + oO + j] = __float2bfloat16(v);
  }
}

// ---------------- gaussian head (setup: z0) ----------------
__global__ __launch_bounds__(256) void k_gauss(
  const bf16* __restrict__ A, const bf16* __restrict__ Bt,
  const float* __restrict__ bias, const float* __restrict__ eps,
  bf16* __restrict__ out, int K)
{
  int lane = threadIdx.x & 63, wave = threadIdx.x >> 6;
  int lr = lane & 15, lq = lane >> 4;
  int j0 = blockIdx.x*64 + wave*16;
  int m0 = blockIdx.y*16;
  const bf16* Ap = A + (m0+lr)*K + lq*8;
  const bf16* Bm = Bt + (j0+lr)*K + lq*8;
  const bf16* Bl = Bt + (j0+1024+lr)*K + lq*8;
  floatx4 aM = {0.f,0.f,0.f,0.f}, aL = {0.f,0.f,0.f,0.f};
  #pragma unroll 4
  for (int kb=0;kb<K;kb+=32){
    short8 a = ldf(Ap+kb);
    aM = MFMA16(a, ldf(Bm+kb), aM);
    aL = MFMA16(a, ldf(Bl+kb), aL);
  }
  #pragma unroll
  for (int i=0;i<4;i++){
    int m = m0+lq*4+i, j = j0+lr;
    float z = aM[i] + bias[j] + __expf(aL[i] + bias[1024+j]) * eps[m*1024 + j];
    out[m*1024+j] = __float2bfloat16(z);
  }
}

// ---------------- scan step kernels: 1024 blocks, 4-way K-split + LDS reduce ----------------
// block b: jt = b&63 (same-XCD per jt: b%8==jt%8), mt = b>>6. Tile 16m x 16j.
__global__ __launch_bounds__(256) void k_gru2(
  const bf16* __restrict__ Z, const bf16* __restrict__ H, const bf16* __restrict__ AE,
  const bf16* __restrict__ WzT, const bf16* __restrict__ WhT, const bf16* __restrict__ WaT,
  const float* __restrict__ bih, const float* __restrict__ bhh,
  bf16* __restrict__ Hn)
{
  __shared__ float red[4][4][64][4];
  const int tid = threadIdx.x, lane = tid & 63, w = tid >> 6;
  const int lr = lane & 15, lq = lane >> 4;
  const int j0 = (blockIdx.x & 63) * 16, m0 = (blockIdx.x >> 6) * 16;
  const int jl = j0 + lr;
  const int c0 = w*640, c1 = c0+640;
  floatx4 R={},U={},NX={},NH={};
  { // Z segment: concat-k [0,1024)
    int hi = c1 < 1024 ? c1 : 1024;
    for (int k=c0; k<hi; k+=32){
      short8 a = ldf(Z + (m0+lr)*1024 + k + lq*8);
      const bf16* bp = WzT + k + lq*8;
      R = MFMA16(a, ldf(bp + (size_t)jl*1024), R);
      U = MFMA16(a, ldf(bp + (size_t)(jl+1024)*1024), U);
      NX= MFMA16(a, ldf(bp + (size_t)(jl+2048)*1024), NX);
    }
  }
  { // AE segment: [1024,1536)
    int lo = c0 > 1024 ? c0 : 1024;
    int hi = c1 < 1536 ? c1 : 1536;
    for (int k=lo; k<hi; k+=32){
      int kk = k - 1024;
      short8 a = ldf(AE + (m0+lr)*512 + kk + lq*8);
      const bf16* bp = WaT + kk + lq*8;
      R = MFMA16(a, ldf(bp + (size_t)jl*512), R);
      U = MFMA16(a, ldf(bp + (size_t)(jl+1024)*512), U);
      NX= MFMA16(a, ldf(bp + (size_t)(jl+2048)*512), NX);
    }
  }
  { // H segment: [1536,2560)
    int lo = c0 > 1536 ? c0 : 1536;
    for (int k=lo; k<c1; k+=32){
      int kk = k - 1536;
      short8 a = ldf(H + (m0+lr)*1024 + kk + lq*8);
      const bf16* bp = WhT + kk + lq*8;
      R = MFMA16(a, ldf(bp + (size_t)jl*1024), R);
      U = MFMA16(a, ldf(bp + (size_t)(jl+1024)*1024), U);
      NH= MFMA16(a, ldf(bp + (size_t)(jl+2048)*1024), NH);
    }
  }
  *(floatx4*)&red[w][0][lane][0]=R;
  *(floatx4*)&red[w][1][lane][0]=U;
  *(floatx4*)&red[w][2][lane][0]=NX;
  *(floatx4*)&red[w][3][lane][0]=NH;
  __syncthreads();
  if (w==0){
    floatx4 sR={},sU={},sNX={},sNH={};
    #pragma unroll
    for (int ww=0;ww<4;ww++){
      sR += *(const floatx4*)&red[ww][0][lane][0];
      sU += *(const floatx4*)&red[ww][1][lane][0];
      sNX+= *(const floatx4*)&red[ww][2][lane][0];
      sNH+= *(const floatx4*)&red[ww][3][lane][0];
    }
    float bR = bih[jl]+bhh[jl];
    float bU = bih[1024+jl]+bhh[1024+jl];
    float bX = bih[2048+jl], bH = bhh[2048+jl];
    #pragma unroll
    for (int i=0;i<4;i++){
      int m = m0 + lq*4 + i;
      float r = fsig(sR[i]+bR);
      float u = fsig(sU[i]+bU);
      float n = ftanh(sNX[i]+bX + r*(sNH[i]+bH));
      float h = __bfloat162float(H[m*1024+jl]);
      Hn[m*1024+jl] = __float2bfloat16((1.f-u)*n + u*h);
    }
  }
}

// X = tanh(Hn @ Lw1 + b1): M=256,N=1024,K=1024; 1024 blocks, wave K-slice 256
__global__ __launch_bounds__(256) void k_lsd1(
  const bf16* __restrict__ Hn, const bf16* __restrict__ Lw1,
  const float* __restrict__ Lb1, bf16* __restrict__ X)
{
  __shared__ float red[4][64][4];
  const int tid = threadIdx.x, lane = tid & 63, w = tid >> 6;
  const int lr = lane & 15, lq = lane >> 4;
  const int j0 = (blockIdx.x & 63) * 16, m0 = (blockIdx.x >> 6) * 16;
  const int jl = j0 + lr;
  floatx4 C={};
  const bf16* Ap = Hn + (m0+lr)*1024 + lq*8;
  const bf16* Bp = Lw1 + (size_t)jl*1024 + lq*8;
  #pragma unroll
  for (int k=w*256; k<w*256+256; k+=32)
    C = MFMA16(ldf(Ap+k), ldf(Bp+k), C);
  *(floatx4*)&red[w][lane][0] = C;
  __syncthreads();
  if (w==0){
    floatx4 s={};
    #pragma unroll
    for (int ww=0;ww<4;ww++) s += *(const floatx4*)&red[ww][lane][0];
    float bb = Lb1[jl];
    #pragma unroll
    for (int i=0;i<4;i++){
      int m = m0 + lq*4 + i;
      X[m*1024+jl] = __float2bfloat16(ftanh(s[i]+bb));
    }
  }
}

// Zn = mu + exp(ls)*eps: M=256,N=1024(2 heads),K=1024; 1024 blocks
__global__ __launch_bounds__(256) void k_lsd2(
  const bf16* __restrict__ X, const bf16* __restrict__ Lw2,
  const float* __restrict__ Lb2, const float* __restrict__ eps,
  bf16* __restrict__ Zn)
{
  __shared__ float red[4][2][64][4];
  const int tid = threadIdx.x, lane = tid & 63, w = tid >> 6;
  const int lr = lane & 15, lq = lane >> 4;
  const int j0 = (blockIdx.x & 63) * 16, m0 = (blockIdx.x >> 6) * 16;
  const int jl = j0 + lr;
  floatx4 M={}, L={};
  const bf16* Ap = X + (m0+lr)*1024 + lq*8;
  const bf16* Bm = Lw2 + (size_t)jl*1024 + lq*8;
  const bf16* Bl = Lw2 + (size_t)(1024+jl)*1024 + lq*8;
  #pragma unroll
  for (int k=w*256; k<w*256+256; k+=32){
    short8 a = ldf(Ap+k);
    M = MFMA16(a, ldf(Bm+k), M);
    L = MFMA16(a, ldf(Bl+k), L);
  }
  *(floatx4*)&red[w][0][lane][0] = M;
  *(floatx4*)&red[w][1][lane][0] = L;
  __syncthreads();
  if (w==0){
    floatx4 sM={}, sL={};
    #pragma unroll
    for (int ww=0;ww<4;ww++){
      sM += *(const floatx4*)&red[ww][0][lane][0];
      sL += *(const floatx4*)&red[ww][1][lane][0];
    }
    float bmu = Lb2[jl], bls = Lb2[1024+jl];
    #pragma unroll
    for (int i=0;i<4;i++){
      int m = m0 + lq*4 + i;
      float z = sM[i]+bmu + __expf(sL[i]+bls) * eps[m*1024+jl];
      Zn[m*1024+jl] = __float2bfloat16(z);
    }
  }
}

// ---------------- decode: 128x128 LDS-tiled GEMM with global_load_lds ----------------
// Y = tanh([Zb|Hb] @ W^T + bias): M=16384, N=1024, K=2048(2 segs). grid (8,128).
__global__ __launch_bounds__(256) void k_dec1v2(
  const bf16* __restrict__ Zb, const bf16* __restrict__ Hb,
  const bf16* __restrict__ W, const float* __restrict__ bias,
  bf16* __restrict__ Y)
{
  __shared__ __align__(16) bf16 As[128*32];
  __shared__ __align__(16) bf16 Bs[128*32];
  const int tid = threadIdx.x, lane = tid & 63, w = tid >> 6;
  const int lr = lane & 15, lq = lane >> 4;
  const int mh = (w & 1) * 64, jh = (w >> 1) * 64;
  const int m0 = blockIdx.y * 128, j0 = blockIdx.x * 128;
  // staging chunk geometry: chunk c in [0,512), row=c>>2, col8=(c&3)*8
  const int cA0 = w*128 + lane,      cA1 = w*128 + 64 + lane;
  const int r0 = cA0>>2, o0 = (cA0&3)*8, r1 = cA1>>2, o1 = (cA1&3)*8;
  bf16* lA0 = As + (w*2+0)*512; bf16* lA1 = As + (w*2+1)*512;
  bf16* lB0 = Bs + (w*2+0)*512; bf16* lB1 = Bs + (w*2+1)*512;
  floatx4 acc[4][4] = {};
  const bf16* Aseg[2] = { Zb + 256*1024, Hb + 256*1024 };
  #pragma unroll
  for (int seg=0; seg<2; seg++){
    const bf16* A = Aseg[seg];
    const bf16* Wb = W + seg*1024;
    for (int kb=0; kb<1024; kb+=32){
      stage16(A  + (size_t)(m0+r0)*1024 + kb + o0, lA0);
      stage16(A  + (size_t)(m0+r1)*1024 + kb + o1, lA1);
      stage16(Wb + (size_t)(j0+r0)*2048 + kb + o0, lB0);
      stage16(Wb + (size_t)(j0+r1)*2048 + kb + o1, lB1);
      __syncthreads();
      short8 af[4], bfr[4];
      #pragma unroll
      for (int f=0; f<4; f++){
        af[f]  = *(const short8*)&As[(mh + f*16 + lr)*32 + lq*8];
        bfr[f] = *(const short8*)&Bs[(jh + f*16 + lr)*32 + lq*8];
      }
      #pragma unroll
      for (int mf=0; mf<4; mf++)
        #pragma unroll
        for (int jf=0; jf<4; jf++)
          acc[mf][jf] = MFMA16(af[mf], bfr[jf], acc[mf][jf]);
      __syncthreads();
    }
  }
  #pragma unroll
  for (int mf=0; mf<4; mf++)
    #pragma unroll
    for (int jf=0; jf<4; jf++)
      #pragma unroll
      for (int i=0; i<4; i++){
        int m = m0 + mh + mf*16 + lq*4 + i;
        int j = j0 + jh + jf*16 + lr;
        Y[(size_t)m*1024 + j] = __float2bfloat16(ftanh(acc[mf][jf][i] + bias[j]));
      }
}

// obs_pred = Y1 @ dec_w2 + b -> out[b][t][0:512]: M=16384,N=512,K=1024. grid (4,128).
__global__ __launch_bounds__(256) void k_out1v2(
  const bf16* __restrict__ Yb, const bf16* __restrict__ W,
  const float* __restrict__ bias, float* __restrict__ out)
{
  __shared__ __align__(16) bf16 As[128*32];
  __shared__ __align__(16) bf16 Bs[128*32];
  const int tid = threadIdx.x, lane = tid & 63, w = tid >> 6;
  const int lr = lane & 15, lq = lane >> 4;
  const int mh = (w & 1) * 64, jh = (w >> 1) * 64;
  const int m0 = blockIdx.y * 128, j0 = blockIdx.x * 128;
  const int cA0 = w*128 + lane,      cA1 = w*128 + 64 + lane;
  const int r0 = cA0>>2, o0 = (cA0&3)*8, r1 = cA1>>2, o1 = (cA1&3)*8;
  bf16* lA0 = As + (w*2+0)*512; bf16* lA1 = As + (w*2+1)*512;
  bf16* lB0 = Bs + (w*2+0)*512; bf16* lB1 = Bs + (w*2+1)*512;
  floatx4 acc[4][4] = {};
  for (int kb=0; kb<1024; kb+=32){
    stage16(Yb + (size_t)(m0+r0)*1024 + kb + o0, lA0);
    stage16(Yb + (size_t)(m0+r1)*1024 + kb + o1, lA1);
    stage16(W  + (size_t)(j0+r0)*1024 + kb + o0, lB0);
    stage16(W  + (size_t)(j0+r1)*1024 + kb + o1, lB1);
    __syncthreads();
    short8 af[4], bfr[4];
    #pragma unroll
    for (int f=0; f<4; f++){
      af[f]  = *(const short8*)&As[(mh + f*16 + lr)*32 + lq*8];
      bfr[f] = *(const short8*)&Bs[(jh + f*16 + lr)*32 + lq*8];
    }
    #pragma unroll
    for (int mf=0; mf<4; mf++)
      #pragma unroll
      for (int jf=0; jf<4; jf++)
        acc[mf][jf] = MFMA16(af[mf], bfr[jf], acc[mf][jf]);
    __syncthreads();
  }
  #pragma unroll
  for (int mf=0; mf<4; mf++)
    #pragma unroll
    for (int jf=0; jf<4; jf++)
      #pragma unroll
      for (int i=0; i<4; i++){
        int m = m0 + mh + mf*16 + lq*4 + i;
        int j = j0 + jh + jf*16 + lr;
        int b = m & 255, t = m >> 8;
        out[(size_t)b*40960 + t*640 + j] = acc[mf][jf][i] + bias[j];
      }
}

// state decoder: din @ sd_w + b -> out[...,512:576]=mu, [...,576:640]=exp(ls)
__global__ __launch_bounds__(256) void k_sd(
  const bf16* __restrict__ Zb, const bf16* __restrict__ Hb,
  const bf16* __restrict__ W, const float* __restrict__ bias,
  float* __restrict__ out)
{
  int lane = threadIdx.x & 63, wave = threadIdx.x >> 6;
  int lr = lane & 15, lq = lane >> 4;
  int m0 = blockIdx.x * 32;
  int j0 = wave * 16;
  floatx4 aM[2] = {}, aL[2] = {};
  const bf16* Az = Zb + 256*1024;
  const bf16* Ah = Hb + 256*1024;
  #pragma unroll 2
  for (int kb=0; kb<1024; kb+=32){
    short8 a0 = ldf(Az + (m0+lr)*1024 + kb + lq*8);
    short8 a1 = ldf(Az + (m0+16+lr)*1024 + kb + lq*8);
    short8 bm = ldf(W + (size_t)(j0+lr)*2048 + kb + lq*8);
    short8 bl = ldf(W + (size_t)(j0+64+lr)*2048 + kb + lq*8);
    aM[0] = MFMA16(a0,bm,aM[0]); aM[1] = MFMA16(a1,bm,aM[1]);
    aL[0] = MFMA16(a0,bl,aL[0]); aL[1] = MFMA16(a1,bl,aL[1]);
  }
  #pragma unroll 2
  for (int kb=0; kb<1024; kb+=32){
    short8 a0 = ldf(Ah + (m0+lr)*1024 + kb + lq*8);
    short8 a1 = ldf(Ah + (m0+16+lr)*1024 + kb + lq*8);
    short8 bm = ldf(W + (size_t)(j0+lr)*2048 + 1024 + kb + lq*8);
    short8 bl = ldf(W + (size_t)(j0+64+lr)*2048 + 1024 + kb + lq*8);
    aM[0] = MFMA16(a0,bm,aM[0]); aM[1] = MFMA16(a1,bm,aM[1]);
    aL[0] = MFMA16(a0,bl,aL[0]); aL[1] = MFMA16(a1,bl,aL[1]);
  }
  #pragma unroll
  for (int rf=0;rf<2;rf++)
    #pragma unroll
    for (int i=0;i<4;i++){
      int m = m0 + rf*16 + lq*4 + i;
      int j = j0 + lr;
      int b = m & 255, t = m >> 8;
      out[b*40960 + t*640 + 512 + j] = aM[rf][i] + bias[j];
      out[b*40960 + t*640 + 576 + j] = __expf(aL[rf][i] + bias[64+j]);
    }
}

extern "C" void kernel_launch(void* const* d_in, const int* in_sizes, int n_in,
                              void* d_out, int out_size, void* d_ws, size_t ws_size,
                              hipStream_t stream)
{
  const float* obs    = (const float*)d_in[0];
  const float* state  = (const float*)d_in[1];
  const float* act    = (const float*)d_in[2];
  const float* eps0   = (const float*)d_in[3];
  const float* epss   = (const float*)d_in[4];
  const float* enc_w1 = (const float*)d_in[5];  const float* enc_b1 = (const float*)d_in[6];
  const float* enc_w2 = (const float*)d_in[7];  const float* enc_b2 = (const float*)d_in[8];
  const float* post_w1= (const float*)d_in[9];  const float* post_b1= (const float*)d_in[10];
  const float* post_w2= (const float*)d_in[11]; const float* post_b2= (const float*)d_in[12];
  const float* amlp_w1= (const float*)d_in[13]; const float* amlp_b1= (const float*)d_in[14];
  const float* amlp_w2= (const float*)d_in[15]; const float* amlp_b2= (const float*)d_in[16];
  const float* gwih   = (const float*)d_in[17];
  const float* gwhh   = (const float*)d_in[18];
  const float* gbih   = (const float*)d_in[19];
  const float* gbhh   = (const float*)d_in[20];
  const float* lsd_w1 = (const float*)d_in[21]; const float* lsd_b1 = (const float*)d_in[22];
  const float* lsd_w2 = (const float*)d_in[23]; const float* lsd_b2 = (const float*)d_in[24];
  const float* dec_w1 = (const float*)d_in[25]; const float* dec_b1 = (const float*)d_in[26];
  const float* dec_w2 = (const float*)d_in[27]; const float* dec_b2 = (const float*)d_in[28];
  const float* sd_w   = (const float*)d_in[29]; const float* sd_b   = (const float*)d_in[30];
  float* out = (float*)d_out;

  char* w = (char*)d_ws;
  size_t off = 0;
  auto alloc = [&](size_t elems)->bf16* {
    bf16* p = (bf16*)(w + off);
    off += ((elems*2 + 255)/256)*256;
    return p;
  };
  bf16* WzT      = alloc((size_t)3072*1024);
  bf16* WhT      = alloc((size_t)3072*1024);
  bf16* WaT      = alloc((size_t)3072*512);
  bf16* lsd_w1T  = alloc((size_t)1024*1024);
  bf16* lsd_w2T  = alloc((size_t)2048*1024);
  bf16* dec_w1T  = alloc((size_t)1024*2048);
  bf16* dec_w2T  = alloc((size_t)512*1024);
  bf16* sd_wT    = alloc((size_t)128*2048);
  bf16* enc_w1T  = alloc((size_t)512*512);
  bf16* enc_w2T  = alloc((size_t)256*512);
  bf16* post_w1sT= alloc((size_t)1024*192);
  bf16* post_w2T = alloc((size_t)2048*1024);
  bf16* amlp_w2T = alloc((size_t)512*512);
  bf16* obsb     = alloc((size_t)256*512);
  bf16* E1       = alloc((size_t)256*512);
  bf16* PIN      = alloc((size_t)256*192);
  bf16* P1       = alloc((size_t)256*1024);
  bf16* X        = alloc((size_t)256*1024);
  bf16* Zbuf     = alloc((size_t)65*256*1024);
  bf16* Hbuf     = alloc((size_t)65*256*1024);
  bf16* AEb      = alloc((size_t)16384*512);
  bf16* Y1       = alloc((size_t)16384*1024);
  bf16* H1       = Y1;   // H1 (16 MiB) dead before Y1 is written

  // --- weight prep ---
  #define TP(src, dst, R, C) k_transpose<<<dim3((C)/32,(R)/32),256,0,stream>>>((src),(dst),(R),(C))
  TP(enc_w1, enc_w1T, 512, 512);
  TP(enc_w2, enc_w2T, 512, 256);
  TP(post_w1 + (size_t)1024*1024, post_w1sT, 192, 1024);
  TP(post_w2, post_w2T, 1024, 2048);
  TP(amlp_w2, amlp_w2T, 512, 512);
  TP(gwih, WzT, 1024, 3072);
  TP(gwih + (size_t)1024*3072, WaT, 512, 3072);
  TP(gwhh, WhT, 1024, 3072);
  TP(lsd_w1, lsd_w1T, 1024, 1024);
  TP(lsd_w2, lsd_w2T, 1024, 2048);
  TP(dec_w1, dec_w1T, 2048, 1024);
  TP(dec_w2, dec_w2T, 1024, 512);
  TP(sd_w, sd_wT, 2048, 128);
  #undef TP

  k_cast<<<512,256,0,stream>>>(obs, obsb, 256*512);
  k_cast_state<<<64,256,0,stream>>>(state, PIN);
  k_acth1<<<32768,256,0,stream>>>(act, amlp_w1, amlp_b1, H1);

  hipMemsetAsync(Hbuf, 0, (size_t)256*1024*2, stream);

  k_gemm16<<<dim3(8,16),256,0,stream>>>(obsb, 512, enc_w1T, enc_b1, E1, 512, 0, 512, 1);
  k_gemm16<<<dim3(2,16),256,0,stream>>>(E1, 512, enc_w2T, enc_b2, PIN, 192, 64, 512, 0);
  k_gemm16<<<dim3(16,16),256,0,stream>>>(PIN, 192, post_w1sT, post_b1, P1, 1024, 0, 192, 1);
  k_gauss<<<dim3(16,16),256,0,stream>>>(P1, post_w2T, post_b2, eps0, Zbuf, 1024);
  k_gemm16<<<dim3(8,1024),256,0,stream>>>(H1, 512, amlp_w2T, amlp_b2, AEb, 512, 0, 512, 0);

  // --- sequential scan: 3 high-occupancy kernels per step ---
  for (int t=0; t<64; t++){
    const bf16* Zt = Zbuf + (size_t)t*262144;
    const bf16* Ht = Hbuf + (size_t)t*262144;
    bf16* Htn = Hbuf + (size_t)(t+1)*262144;
    bf16* Ztn = Zbuf + (size_t)(t+1)*262144;
    k_gru2<<<1024,256,0,stream>>>(Zt, Ht, AEb + (size_t)t*131072, WzT, WhT, WaT, gbih, gbhh, Htn);
    k_lsd1<<<1024,256,0,stream>>>(Htn, lsd_w1T, lsd_b1, X);
    k_lsd2<<<1024,256,0,stream>>>(X, lsd_w2T, lsd_b2, epss + (size_t)t*262144, Ztn);
  }

  // --- decode ---
  k_dec1v2<<<dim3(8,128),256,0,stream>>>(Zbuf, Hbuf, dec_w1T, dec_b1, Y1);
  k_out1v2<<<dim3(4,128),256,0,stream>>>(Y1, dec_w2T, dec_b2, out);
  k_sd<<<512,256,0,stream>>>(Zbuf, Hbuf, sd_wT, sd_b, out);
}